// Round 3
// baseline (1244.403 us; speedup 1.0000x reference)
//
#include <hip/hip_runtime.h>

#define S_STEPS 8
#define D 128

typedef __attribute__((ext_vector_type(4))) float f32x4;
typedef __attribute__((ext_vector_type(4))) short s16x4;
typedef __attribute__((ext_vector_type(8))) short s16x8;

static __device__ __forceinline__ short f2bf(float f) {
    union { float f; unsigned u; } x; x.f = f;
    unsigned r = x.u + 0x7fffu + ((x.u >> 16) & 1u);
    return (short)(r >> 16);
}

__global__ void count_kernel(const int* __restrict__ dst, int* __restrict__ cnt, int E) {
    int e = blockIdx.x * blockDim.x + threadIdx.x;
    if (e < E) atomicAdd(&cnt[dst[e]], 1);
}

// bf16 conversion of [Wl;Wr] -> wbf[256][128], once per call
__global__ void cvtw_kernel(const float* __restrict__ Wl, const float* __restrict__ Wr,
                            unsigned short* __restrict__ wbf) {
    int i = blockIdx.x * blockDim.x + threadIdx.x;   // 0..32767
    if (i < 256 * 128) {
        int j = i >> 7, k = i & 127;
        float v = (j < 128) ? Wl[j * 128 + k] : Wr[(j - 128) * 128 + k];
        wbf[i] = (unsigned short)f2bf(v);
    }
}

// Single-block scan over cnt -> row_ptr (exclusive), fill init, rdeg. Shuffle-based.
__global__ __launch_bounds__(1024) void scan_kernel(const int* __restrict__ cnt,
                            int* __restrict__ row_ptr,
                            int* __restrict__ fill, float* __restrict__ rdeg,
                            int N, int E) {
    __shared__ int wsum[16];
    __shared__ int woff[16];
    __shared__ int carry_s;
    const int tid = threadIdx.x;
    const int lane = tid & 63;
    const int wv = tid >> 6;
    if (tid == 0) carry_s = 0;
    __syncthreads();
    for (int base = 0; base < N; base += 1024) {
        int i = base + tid;
        int v = (i < N) ? cnt[i] : 0;
        int inc = v;
#pragma unroll
        for (int off = 1; off < 64; off <<= 1) {
            int t = __shfl_up(inc, off);
            if (lane >= off) inc += t;
        }
        if (lane == 63) wsum[wv] = inc;
        __syncthreads();
        if (wv == 0 && lane < 16) {
            int s = wsum[lane];
            int in2 = s;
#pragma unroll
            for (int off = 1; off < 16; off <<= 1) {
                int t = __shfl_up(in2, off);
                if (lane >= off) in2 += t;
            }
            woff[lane] = in2 - s;   // exclusive wave offset
        }
        __syncthreads();
        int carry = carry_s;
        int excl = carry + woff[wv] + inc - v;
        if (i < N) {
            row_ptr[i] = excl;
            fill[i] = excl;
            rdeg[i] = 1.0f / (float)((v > 1) ? v : 1);
        }
        __syncthreads();            // everyone read carry_s before update
        if (tid == 1023) carry_s = carry + woff[15] + inc;
        __syncthreads();
    }
    if (tid == 0) row_ptr[N] = E;
}

__global__ void fill_kernel(const int* __restrict__ src, const int* __restrict__ dst,
                            int* __restrict__ fill, int* __restrict__ eidx, int E) {
    int e = blockIdx.x * blockDim.x + threadIdx.x;
    if (e < E) {
        int p = atomicAdd(&fill[dst[e]], 1);
        eidx[p] = src[e];
    }
}

// C[N,256] = bf16(x[N,128]) @ wbf^T. Waves 0,1 -> cols 0..127 -> hbf with layout
// hbf[node][step slot tf of SF][128]; waves 2,3 -> cols 128..255 ->
// outb = x@Wr^T + b_l. B fragments live in registers; only A tile staged in LDS.
__global__ __launch_bounds__(256) void lin_kernel(const float* __restrict__ x,
    const unsigned short* __restrict__ wbf, const float* __restrict__ bl,
    unsigned short* __restrict__ hbf, float* __restrict__ outb, int N,
    int SF, int tf)
{
    __shared__ __align__(16) short As[64 * 136];   // pitch 136 -> bank spread
    __shared__ float bls[128];

    const int tid = threadIdx.x;
    const int row0 = blockIdx.x * 64;
    const int lane = tid & 63;
    const int w = tid >> 6;
    const int m = lane & 15;
    const int q = lane >> 4;

    // B register staging: wave w owns cols w*64 .. w*64+63 (4 col-tiles)
    s16x8 bf[4][4];
#pragma unroll
    for (int ct = 0; ct < 4; ++ct) {
#pragma unroll
        for (int kc = 0; kc < 4; ++kc) {
            int col = (w * 4 + ct) * 16 + m;
            bf[ct][kc] = *(const s16x8*)(wbf + (size_t)col * 128 + kc * 32 + q * 8);
        }
    }
    if (tid < 128) bls[tid] = bl[tid];

    // stage A: 64 rows of x, fp32 -> bf16 LDS
#pragma unroll
    for (int it = 0; it < 8; ++it) {
        int i = tid + it * 256;            // 0..2047
        int r = i >> 5;                    // local row
        int kq = i & 31;                   // float4 index along K
        int grow = row0 + r;
        float4 v = make_float4(0.f, 0.f, 0.f, 0.f);
        if (grow < N) v = *(const float4*)(x + (size_t)grow * 128 + kq * 4);
        s16x4 a; a.x = f2bf(v.x); a.y = f2bf(v.y); a.z = f2bf(v.z); a.w = f2bf(v.w);
        *(s16x4*)&As[r * 136 + kq * 4] = a;
    }
    __syncthreads();

    f32x4 acc[4][4];
#pragma unroll
    for (int i = 0; i < 4; ++i)
#pragma unroll
        for (int j = 0; j < 4; ++j) acc[i][j] = (f32x4){0.f, 0.f, 0.f, 0.f};

#pragma unroll
    for (int mt = 0; mt < 4; ++mt) {
        s16x8 af[4];
#pragma unroll
        for (int kc = 0; kc < 4; ++kc)
            af[kc] = *(const s16x8*)&As[(mt * 16 + m) * 136 + kc * 32 + q * 8];
#pragma unroll
        for (int ct = 0; ct < 4; ++ct)
#pragma unroll
            for (int kc = 0; kc < 4; ++kc)
                acc[mt][ct] = __builtin_amdgcn_mfma_f32_16x16x32_bf16(
                    af[kc], bf[ct][kc], acc[mt][ct], 0, 0, 0);
    }

    const int colbase = w * 64;
#pragma unroll
    for (int mt = 0; mt < 4; ++mt) {
        const int rowbase = row0 + mt * 16 + q * 4;
#pragma unroll
        for (int ct = 0; ct < 4; ++ct) {
            int col = colbase + ct * 16 + m;
#pragma unroll
            for (int r = 0; r < 4; ++r) {
                int rr = rowbase + r;
                if (rr < N) {
                    if (col < 128) {
                        hbf[((size_t)rr * SF + tf) * 128 + col] =
                            (unsigned short)f2bf(acc[mt][ct][r]);
                    } else {
                        outb[(size_t)rr * 128 + (col - 128)] = acc[mt][ct][r] + bls[col - 128];
                    }
                }
            }
        }
    }
}

#define BF2ACC(u, j) { union { unsigned v; float f; } lo_, hi_; \
    lo_.v = (u) << 16; hi_.v = (u) & 0xffff0000u; \
    acc[j] += lo_.f; acc[(j) + 1] += hi_.f; }
#define ACC8(p, j) { BF2ACC((p).x, (j)); BF2ACC((p).y, (j) + 2); \
    BF2ACC((p).z, (j) + 4); BF2ACC((p).w, (j) + 6); }

// Fused 8-step CSR gather. One wave per node. Lane l owns (step = l>>3,
// feats = (l&7)*16 .. +15) == exactly bytes [l*32, l*32+32) of the node's
// 2KB hbf row, so each edge is one contiguous 2KB wave read (2x dwordx4/lane)
// and no cross-lane reduction is needed for the aggregation.
__global__ __launch_bounds__(256) void agg8_kernel(const unsigned short* __restrict__ hbf,
    const int* __restrict__ row_ptr, const int* __restrict__ eidx,
    const float* __restrict__ rdeg, const float* __restrict__ wfc,
    const float* __restrict__ bfc, float* __restrict__ xs,
    float* __restrict__ ys, int N)
{
    const int lane = threadIdx.x & 63;
    const int wv = threadIdx.x >> 6;
    const int node = blockIdx.x * 4 + wv;
    if (node >= N) return;

    const int beg = row_ptr[node];
    const int end = row_ptr[node + 1];

    float acc[16];
#pragma unroll
    for (int j = 0; j < 16; ++j) acc[j] = 0.f;

    const uint4* hb = (const uint4*)hbf;   // node row = 128 uint4 (2KB)

    int e = beg;
    for (; e + 2 <= end; e += 2) {
        int s0 = eidx[e];
        int s1 = eidx[e + 1];
        const uint4* q0 = hb + (size_t)s0 * 128 + lane * 2;
        const uint4* q1 = hb + (size_t)s1 * 128 + lane * 2;
        uint4 a0 = q0[0];
        uint4 a1 = q0[1];
        uint4 b0 = q1[0];
        uint4 b1 = q1[1];
        ACC8(a0, 0); ACC8(a1, 8);
        ACC8(b0, 0); ACC8(b1, 8);
    }
    if (e < end) {
        int s0 = eidx[e];
        const uint4* q0 = hb + (size_t)s0 * 128 + lane * 2;
        uint4 a0 = q0[0];
        uint4 a1 = q0[1];
        ACC8(a0, 0); ACC8(a1, 8);
    }

    const int t = lane >> 3;
    const int fb = (lane & 7) * 16;
    const float rd = rdeg[node];

    float* orow = xs + ((size_t)t * N + node) * 128 + fb;
    float4 o[4];
#pragma unroll
    for (int j = 0; j < 4; ++j) o[j] = *((const float4*)orow + j);
#pragma unroll
    for (int j = 0; j < 4; ++j) {
        o[j].x += acc[j * 4 + 0] * rd;
        o[j].y += acc[j * 4 + 1] * rd;
        o[j].z += acc[j * 4 + 2] * rd;
        o[j].w += acc[j * 4 + 3] * rd;
    }
#pragma unroll
    for (int j = 0; j < 4; ++j) {
        f32x4 ov = {o[j].x, o[j].y, o[j].z, o[j].w};
        __builtin_nontemporal_store(ov, (f32x4*)orow + j);
    }

    const float4* wv4 = (const float4*)(wfc + fb);
    float p = 0.f;
#pragma unroll
    for (int j = 0; j < 4; ++j) {
        float4 w4 = wv4[j];
        p += o[j].x * w4.x + o[j].y * w4.y + o[j].z * w4.z + o[j].w * w4.w;
    }
    p += __shfl_xor(p, 1);
    p += __shfl_xor(p, 2);
    p += __shfl_xor(p, 4);
    if ((lane & 7) == 0) ys[(size_t)t * N + node] = p + bfc[0];
}

// Fallback (round-0 proven): per-step CSR gather of h (bf16), 4 edges per
// wave-iteration, dwordx4/lane.
__global__ __launch_bounds__(256) void agg_kernel(const unsigned short* __restrict__ hbf,
    const int* __restrict__ row_ptr, const int* __restrict__ eidx,
    const float* __restrict__ rdeg, const float* __restrict__ wfc,
    const float* __restrict__ bfc, float* __restrict__ outb,
    float* __restrict__ ys, int N)
{
    const int lane = threadIdx.x & 63;
    const int wv = threadIdx.x >> 6;
    const int node = blockIdx.x * 4 + wv;
    if (node >= N) return;
    const int g = lane >> 4;
    const int l = lane & 15;
    const int beg = row_ptr[node];
    const int end = row_ptr[node + 1];

    float acc[8];
#pragma unroll
    for (int j = 0; j < 8; ++j) acc[j] = 0.f;

    const unsigned short* hb = hbf + l * 8;
#pragma unroll 2
    for (int e = beg + g; e < end; e += 4) {
        int s = eidx[e];
        uint4 pk = *(const uint4*)(hb + (size_t)s * 128);
        union { unsigned u; float f; } t;
        t.u = pk.x << 16;        acc[0] += t.f;
        t.u = pk.x & 0xffff0000u; acc[1] += t.f;
        t.u = pk.y << 16;        acc[2] += t.f;
        t.u = pk.y & 0xffff0000u; acc[3] += t.f;
        t.u = pk.z << 16;        acc[4] += t.f;
        t.u = pk.z & 0xffff0000u; acc[5] += t.f;
        t.u = pk.w << 16;        acc[6] += t.f;
        t.u = pk.w & 0xffff0000u; acc[7] += t.f;
    }
#pragma unroll
    for (int j = 0; j < 8; ++j) {
        acc[j] += __shfl_xor(acc[j], 16);
        acc[j] += __shfl_xor(acc[j], 32);
    }
    float ax = (g == 0) ? acc[0] : (g == 1) ? acc[2] : (g == 2) ? acc[4] : acc[6];
    float ay = (g == 0) ? acc[1] : (g == 1) ? acc[3] : (g == 2) ? acc[5] : acc[7];

    const int feat = l * 8 + g * 2;
    const float rd = rdeg[node];
    const float2 base = *(const float2*)(outb + (size_t)node * 128 + feat);
    float ox = base.x + ax * rd;
    float oy = base.y + ay * rd;
    *(float2*)(outb + (size_t)node * 128 + feat) = make_float2(ox, oy);

    const float2 wv2 = *(const float2*)(wfc + feat);
    float p = ox * wv2.x + oy * wv2.y;
#pragma unroll
    for (int off = 32; off > 0; off >>= 1) p += __shfl_down(p, off);
    if (lane == 0) ys[node] = p + bfc[0];
}

extern "C" void kernel_launch(void* const* d_in, const int* in_sizes, int n_in,
                              void* d_out, int out_size, void* d_ws, size_t ws_size,
                              hipStream_t stream)
{
    const float* x   = (const float*)d_in[0];
    const int*   ei  = (const int*)d_in[1];
    const float* Wl  = (const float*)d_in[2];
    const float* bl  = (const float*)d_in[3];
    const float* Wr  = (const float*)d_in[4];
    const float* Wfc = (const float*)d_in[5];
    const float* bfc = (const float*)d_in[6];

    const int N = in_sizes[0] / (S_STEPS * D);
    const int E = in_sizes[1] / 2;
    const int* srcp = ei;
    const int* dstp = ei + E;

    char* p = (char*)d_ws;
    auto alloc = [&](size_t bytes) {
        char* r = p;
        p += (bytes + 255) & ~(size_t)255;
        return r;
    };
    int*   cnt     = (int*)alloc((size_t)N * 4);
    int*   row_ptr = (int*)alloc((size_t)(N + 1) * 4);
    int*   fill    = (int*)alloc((size_t)N * 4);
    float* rdeg    = (float*)alloc((size_t)N * 4);
    int*   eidx    = (int*)alloc((size_t)E * 4);
    unsigned short* wbf = (unsigned short*)alloc((size_t)256 * 128 * 2);

    // Fused path needs node-major H for all steps: [N][S][128] bf16 (~102 MB).
    // Only take it if the workspace actually has room.
    size_t used = (size_t)(p - (char*)d_ws);
    size_t need8 = (size_t)N * S_STEPS * D * 2;
    bool fused = (ws_size >= used + need8 + 4096);
    unsigned short* hbf = (unsigned short*)alloc(fused ? need8 : (size_t)N * D * 2);

    float* xs    = (float*)d_out;
    float* ysall = xs + (size_t)S_STEPS * N * D;

    (void)hipMemsetAsync(cnt, 0, (size_t)N * 4, stream);
    cvtw_kernel<<<128, 256, 0, stream>>>(Wl, Wr, wbf);
    count_kernel<<<(E + 255) / 256, 256, 0, stream>>>(dstp, cnt, E);
    scan_kernel<<<1, 1024, 0, stream>>>(cnt, row_ptr, fill, rdeg, N, E);
    fill_kernel<<<(E + 255) / 256, 256, 0, stream>>>(srcp, dstp, fill, eidx, E);

    const int gl = (N + 63) / 64;
    const int ga = (N + 3) / 4;
    if (fused) {
        for (int t = 0; t < S_STEPS; ++t) {
            const float* xt = x + (size_t)t * N * D;
            float* outb = xs + (size_t)t * N * D;
            lin_kernel<<<gl, 256, 0, stream>>>(xt, wbf, bl, hbf, outb, N,
                                               S_STEPS, t);
        }
        agg8_kernel<<<ga, 256, 0, stream>>>(hbf, row_ptr, eidx, rdeg, Wfc, bfc,
                                            xs, ysall, N);
    } else {
        for (int t = 0; t < S_STEPS; ++t) {
            const float* xt = x + (size_t)t * N * D;
            float* outb = xs + (size_t)t * N * D;
            lin_kernel<<<gl, 256, 0, stream>>>(xt, wbf, bl, hbf, outb, N, 1, 0);
            agg_kernel<<<ga, 256, 0, stream>>>(hbf, row_ptr, eidx, rdeg, Wfc, bfc,
                                               outb, ysall + (size_t)t * N, N);
        }
    }
}

// Round 4
// 1141.322 us; speedup vs baseline: 1.0903x; 1.0903x over previous
//
#include <hip/hip_runtime.h>

#define S_STEPS 8
#define D 128

typedef __attribute__((ext_vector_type(4))) float f32x4;
typedef __attribute__((ext_vector_type(4))) short s16x4;
typedef __attribute__((ext_vector_type(8))) short s16x8;

static __device__ __forceinline__ short f2bf(float f) {
    union { float f; unsigned u; } x; x.f = f;
    unsigned r = x.u + 0x7fffu + ((x.u >> 16) & 1u);
    return (short)(r >> 16);
}

__global__ void count_kernel(const int* __restrict__ dst, int* __restrict__ cnt, int E) {
    int e = blockIdx.x * blockDim.x + threadIdx.x;
    if (e < E) atomicAdd(&cnt[dst[e]], 1);
}

// bf16 conversion of [Wl;Wr] -> wbf[256][128] (v0 fallback path)
__global__ void cvtw_kernel(const float* __restrict__ Wl, const float* __restrict__ Wr,
                            unsigned short* __restrict__ wbf) {
    int i = blockIdx.x * blockDim.x + threadIdx.x;   // 0..32767
    if (i < 256 * 128) {
        int j = i >> 7, k = i & 127;
        float v = (j < 128) ? Wl[j * 128 + k] : Wr[(j - 128) * 128 + k];
        wbf[i] = (unsigned short)f2bf(v);
    }
}

// v4: wcat[128][256]: row j = [Wl[j][0:128] | Wr[j][0:128]] in bf16
__global__ void cvtwcat_kernel(const float* __restrict__ Wl, const float* __restrict__ Wr,
                               unsigned short* __restrict__ wcat) {
    int i = blockIdx.x * blockDim.x + threadIdx.x;   // 0..32767
    if (i < 128 * 256) {
        int j = i >> 8, k = i & 255;
        float v = (k < 128) ? Wl[j * 128 + k] : Wr[j * 128 + (k - 128)];
        wcat[i] = (unsigned short)f2bf(v);
    }
}

// v4: x [S][N][128] fp32 -> xbf [N][S][128] bf16 (node-major). One wave per node.
__global__ __launch_bounds__(256) void cvtx_kernel(const float* __restrict__ x,
    unsigned short* __restrict__ xbf, int N)
{
    const int lane = threadIdx.x & 63;
    const int wv = threadIdx.x >> 6;
    const int node = blockIdx.x * 4 + wv;
    if (node >= N) return;
#pragma unroll
    for (int t = 0; t < S_STEPS; ++t) {
        float2 v = *(const float2*)(x + ((size_t)t * N + node) * 128 + lane * 2);
        ushort2 u;
        u.x = (unsigned short)f2bf(v.x);
        u.y = (unsigned short)f2bf(v.y);
        *(ushort2*)(xbf + ((size_t)node * S_STEPS + t) * 128 + lane * 2) = u;
    }
}

// Single-block scan over cnt -> row_ptr (exclusive), fill init, rdeg. Shuffle-based.
__global__ __launch_bounds__(1024) void scan_kernel(const int* __restrict__ cnt,
                            int* __restrict__ row_ptr,
                            int* __restrict__ fill, float* __restrict__ rdeg,
                            int N, int E) {
    __shared__ int wsum[16];
    __shared__ int woff[16];
    __shared__ int carry_s;
    const int tid = threadIdx.x;
    const int lane = tid & 63;
    const int wv = tid >> 6;
    if (tid == 0) carry_s = 0;
    __syncthreads();
    for (int base = 0; base < N; base += 1024) {
        int i = base + tid;
        int v = (i < N) ? cnt[i] : 0;
        int inc = v;
#pragma unroll
        for (int off = 1; off < 64; off <<= 1) {
            int t = __shfl_up(inc, off);
            if (lane >= off) inc += t;
        }
        if (lane == 63) wsum[wv] = inc;
        __syncthreads();
        if (wv == 0 && lane < 16) {
            int s = wsum[lane];
            int in2 = s;
#pragma unroll
            for (int off = 1; off < 16; off <<= 1) {
                int t = __shfl_up(in2, off);
                if (lane >= off) in2 += t;
            }
            woff[lane] = in2 - s;   // exclusive wave offset
        }
        __syncthreads();
        int carry = carry_s;
        int excl = carry + woff[wv] + inc - v;
        if (i < N) {
            row_ptr[i] = excl;
            fill[i] = excl;
            rdeg[i] = 1.0f / (float)((v > 1) ? v : 1);
        }
        __syncthreads();            // everyone read carry_s before update
        if (tid == 1023) carry_s = carry + woff[15] + inc;
        __syncthreads();
    }
    if (tid == 0) row_ptr[N] = E;
}

__global__ void fill_kernel(const int* __restrict__ src, const int* __restrict__ dst,
                            int* __restrict__ fill, int* __restrict__ eidx, int E) {
    int e = blockIdx.x * blockDim.x + threadIdx.x;
    if (e < E) {
        int p = atomicAdd(&fill[dst[e]], 1);
        eidx[p] = src[e];
    }
}

// v0 fallback: C[N,256] = bf16(x[N,128]) @ wbf^T. Waves 0,1 -> hbf; waves 2,3 ->
// outb = x@Wr^T + b_l.
__global__ __launch_bounds__(256) void lin_kernel(const float* __restrict__ x,
    const unsigned short* __restrict__ wbf, const float* __restrict__ bl,
    unsigned short* __restrict__ hbf, float* __restrict__ outb, int N,
    int SF, int tf)
{
    __shared__ __align__(16) short As[64 * 136];   // pitch 136 -> bank spread
    __shared__ float bls[128];

    const int tid = threadIdx.x;
    const int row0 = blockIdx.x * 64;
    const int lane = tid & 63;
    const int w = tid >> 6;
    const int m = lane & 15;
    const int q = lane >> 4;

    s16x8 bf[4][4];
#pragma unroll
    for (int ct = 0; ct < 4; ++ct) {
#pragma unroll
        for (int kc = 0; kc < 4; ++kc) {
            int col = (w * 4 + ct) * 16 + m;
            bf[ct][kc] = *(const s16x8*)(wbf + (size_t)col * 128 + kc * 32 + q * 8);
        }
    }
    if (tid < 128) bls[tid] = bl[tid];

#pragma unroll
    for (int it = 0; it < 8; ++it) {
        int i = tid + it * 256;            // 0..2047
        int r = i >> 5;                    // local row
        int kq = i & 31;                   // float4 index along K
        int grow = row0 + r;
        float4 v = make_float4(0.f, 0.f, 0.f, 0.f);
        if (grow < N) v = *(const float4*)(x + (size_t)grow * 128 + kq * 4);
        s16x4 a; a.x = f2bf(v.x); a.y = f2bf(v.y); a.z = f2bf(v.z); a.w = f2bf(v.w);
        *(s16x4*)&As[r * 136 + kq * 4] = a;
    }
    __syncthreads();

    f32x4 acc[4][4];
#pragma unroll
    for (int i = 0; i < 4; ++i)
#pragma unroll
        for (int j = 0; j < 4; ++j) acc[i][j] = (f32x4){0.f, 0.f, 0.f, 0.f};

#pragma unroll
    for (int mt = 0; mt < 4; ++mt) {
        s16x8 af[4];
#pragma unroll
        for (int kc = 0; kc < 4; ++kc)
            af[kc] = *(const s16x8*)&As[(mt * 16 + m) * 136 + kc * 32 + q * 8];
#pragma unroll
        for (int ct = 0; ct < 4; ++ct)
#pragma unroll
            for (int kc = 0; kc < 4; ++kc)
                acc[mt][ct] = __builtin_amdgcn_mfma_f32_16x16x32_bf16(
                    af[kc], bf[ct][kc], acc[mt][ct], 0, 0, 0);
    }

    const int colbase = w * 64;
#pragma unroll
    for (int mt = 0; mt < 4; ++mt) {
        const int rowbase = row0 + mt * 16 + q * 4;
#pragma unroll
        for (int ct = 0; ct < 4; ++ct) {
            int col = colbase + ct * 16 + m;
#pragma unroll
            for (int r = 0; r < 4; ++r) {
                int rr = rowbase + r;
                if (rr < N) {
                    if (col < 128) {
                        hbf[((size_t)rr * SF + tf) * 128 + col] =
                            (unsigned short)f2bf(acc[mt][ct][r]);
                    } else {
                        outb[(size_t)rr * 128 + (col - 128)] = acc[mt][ct][r] + bls[col - 128];
                    }
                }
            }
        }
    }
}

#define BF2ACC(u, j) { union { unsigned v; float f; } lo_, hi_; \
    lo_.v = (u) << 16; hi_.v = (u) & 0xffff0000u; \
    acc[j] += lo_.f; acc[(j) + 1] += hi_.f; }
#define ACC8(p, j) { BF2ACC((p).x, (j)); BF2ACC((p).y, (j) + 2); \
    BF2ACC((p).z, (j) + 4); BF2ACC((p).w, (j) + 6); }

// v4: pure fused 8-step gather over node-major xbf -> mean -> aggx (bf16, NT).
// One wave per node; lane l owns bytes [l*32, l*32+32) of the 2KB node row.
// No xs traffic, no fc: the only L3 competitor is eidx, so xbf stays resident.
__global__ __launch_bounds__(256) void agg8x_kernel(const unsigned short* __restrict__ xbf,
    const int* __restrict__ row_ptr, const int* __restrict__ eidx,
    const float* __restrict__ rdeg, unsigned short* __restrict__ aggx, int N)
{
    const int lane = threadIdx.x & 63;
    const int wv = threadIdx.x >> 6;
    const int node = blockIdx.x * 4 + wv;
    if (node >= N) return;

    const int beg = row_ptr[node];
    const int end = row_ptr[node + 1];

    float acc[16];
#pragma unroll
    for (int j = 0; j < 16; ++j) acc[j] = 0.f;

    const uint4* hb = (const uint4*)xbf;   // node row = 128 uint4 (2KB)

    int e = beg;
    for (; e + 2 <= end; e += 2) {
        int s0 = eidx[e];
        int s1 = eidx[e + 1];
        const uint4* q0 = hb + (size_t)s0 * 128 + lane * 2;
        const uint4* q1 = hb + (size_t)s1 * 128 + lane * 2;
        uint4 a0 = q0[0];
        uint4 a1 = q0[1];
        uint4 b0 = q1[0];
        uint4 b1 = q1[1];
        ACC8(a0, 0); ACC8(a1, 8);
        ACC8(b0, 0); ACC8(b1, 8);
    }
    if (e < end) {
        int s0 = eidx[e];
        const uint4* q0 = hb + (size_t)s0 * 128 + lane * 2;
        uint4 a0 = q0[0];
        uint4 a1 = q0[1];
        ACC8(a0, 0); ACC8(a1, 8);
    }

    const float rd = rdeg[node];
    unsigned short* orow = aggx + (size_t)node * (S_STEPS * 128) + lane * 16;
    s16x8 o0, o1;
#pragma unroll
    for (int j = 0; j < 8; ++j) {
        o0[j] = f2bf(acc[j] * rd);
        o1[j] = f2bf(acc[8 + j] * rd);
    }
    __builtin_nontemporal_store(o0, (s16x8*)orow);
    __builtin_nontemporal_store(o1, (s16x8*)orow + 1);
}

// v4: out[row=(n,t)][128] = [aggx|xbf] @ wcat^T + bl ; ys = out . wfc + bfc.
// M-tile = 64 rows = 8 nodes x 8 steps; K = 256; 4 waves each own 32 out-cols.
__global__ __launch_bounds__(256) void lin2_kernel(
    const unsigned short* __restrict__ aggx, const unsigned short* __restrict__ xbf,
    const unsigned short* __restrict__ wcat, const float* __restrict__ bl,
    const float* __restrict__ wfc, const float* __restrict__ bfc,
    float* __restrict__ xs, float* __restrict__ ys, int N)
{
    __shared__ __align__(16) short As[64 * 264];   // pitch 264 -> bank spread
    __shared__ float bls[128];
    __shared__ float wfs[128];
    __shared__ float part[4][64];

    const int tid = threadIdx.x;
    const int node0 = blockIdx.x * 8;
    const int lane = tid & 63;
    const int w = tid >> 6;
    const int m = lane & 15;
    const int q = lane >> 4;

    // B frags: wave w owns out-cols w*32 .. w*32+31, K=256 in 8 chunks
    s16x8 bf[2][8];
#pragma unroll
    for (int ct = 0; ct < 2; ++ct) {
#pragma unroll
        for (int kc = 0; kc < 8; ++kc) {
            int col = w * 32 + ct * 16 + m;
            bf[ct][kc] = *(const s16x8*)(wcat + (size_t)col * 256 + kc * 32 + q * 8);
        }
    }
    if (tid < 128) { bls[tid] = bl[tid]; wfs[tid] = wfc[tid]; }

    // stage A: 8 nodes; left half <- aggx node row (2KB), right half <- xbf
#pragma unroll
    for (int it = 0; it < 4; ++it) {
        int c = tid + it * 256;            // 0..1023
        int nl = c >> 7;                   // 0..7 local node
        int j = c & 127;                   // 16B chunk within node row
        int t = j >> 4;
        int k16 = j & 15;
        int row = nl * 8 + t;
        int node = node0 + nl;
        s16x8 va = (s16x8){0,0,0,0,0,0,0,0};
        s16x8 vx = (s16x8){0,0,0,0,0,0,0,0};
        if (node < N) {
            size_t src = ((size_t)node * S_STEPS + t) * 128 + k16 * 8;
            va = *(const s16x8*)(aggx + src);
            vx = *(const s16x8*)(xbf + src);
        }
        *(s16x8*)&As[row * 264 + k16 * 8] = va;
        *(s16x8*)&As[row * 264 + 128 + k16 * 8] = vx;
    }
    __syncthreads();

    f32x4 acc[4][2];
#pragma unroll
    for (int i = 0; i < 4; ++i)
#pragma unroll
        for (int j = 0; j < 2; ++j) acc[i][j] = (f32x4){0.f, 0.f, 0.f, 0.f};

#pragma unroll
    for (int mt = 0; mt < 4; ++mt) {
        s16x8 af[8];
#pragma unroll
        for (int kc = 0; kc < 8; ++kc)
            af[kc] = *(const s16x8*)&As[(mt * 16 + m) * 264 + kc * 32 + q * 8];
#pragma unroll
        for (int ct = 0; ct < 2; ++ct)
#pragma unroll
            for (int kc = 0; kc < 8; ++kc)
                acc[mt][ct] = __builtin_amdgcn_mfma_f32_16x16x32_bf16(
                    af[kc], bf[ct][kc], acc[mt][ct], 0, 0, 0);
    }

    // epilogue: bias, store xs, partial fc dot
    float pd[4][4];
#pragma unroll
    for (int i = 0; i < 4; ++i)
#pragma unroll
        for (int r = 0; r < 4; ++r) pd[i][r] = 0.f;

    const int colb = w * 32;
#pragma unroll
    for (int mt = 0; mt < 4; ++mt) {
#pragma unroll
        for (int ct = 0; ct < 2; ++ct) {
            int col = colb + ct * 16 + m;
            float blv = bls[col];
            float wfv = wfs[col];
#pragma unroll
            for (int r = 0; r < 4; ++r) {
                int row = mt * 16 + q * 4 + r;     // local row
                int node = node0 + (row >> 3);
                int t = row & 7;
                float o = acc[mt][ct][r] + blv;
                if (node < N) xs[((size_t)t * N + node) * 128 + col] = o;
                pd[mt][r] += o * wfv;
            }
        }
    }
    // reduce partial dots across the 16 m-lanes
#pragma unroll
    for (int off = 1; off < 16; off <<= 1)
#pragma unroll
        for (int mt = 0; mt < 4; ++mt)
#pragma unroll
            for (int r = 0; r < 4; ++r)
                pd[mt][r] += __shfl_xor(pd[mt][r], off);
    if (m == 0) {
#pragma unroll
        for (int mt = 0; mt < 4; ++mt)
#pragma unroll
            for (int r = 0; r < 4; ++r)
                part[w][mt * 16 + q * 4 + r] = pd[mt][r];
    }
    __syncthreads();
    if (tid < 64) {
        int row = tid;
        float v = part[0][row] + part[1][row] + part[2][row] + part[3][row] + bfc[0];
        int node = node0 + (row >> 3);
        int t = row & 7;
        if (node < N) ys[(size_t)t * N + node] = v;
    }
}

// v0 fallback: per-step CSR gather of h (bf16)
__global__ __launch_bounds__(256) void agg_kernel(const unsigned short* __restrict__ hbf,
    const int* __restrict__ row_ptr, const int* __restrict__ eidx,
    const float* __restrict__ rdeg, const float* __restrict__ wfc,
    const float* __restrict__ bfc, float* __restrict__ outb,
    float* __restrict__ ys, int N)
{
    const int lane = threadIdx.x & 63;
    const int wv = threadIdx.x >> 6;
    const int node = blockIdx.x * 4 + wv;
    if (node >= N) return;
    const int g = lane >> 4;
    const int l = lane & 15;
    const int beg = row_ptr[node];
    const int end = row_ptr[node + 1];

    float acc[8];
#pragma unroll
    for (int j = 0; j < 8; ++j) acc[j] = 0.f;

    const unsigned short* hb = hbf + l * 8;
#pragma unroll 2
    for (int e = beg + g; e < end; e += 4) {
        int s = eidx[e];
        uint4 pk = *(const uint4*)(hb + (size_t)s * 128);
        union { unsigned u; float f; } t;
        t.u = pk.x << 16;        acc[0] += t.f;
        t.u = pk.x & 0xffff0000u; acc[1] += t.f;
        t.u = pk.y << 16;        acc[2] += t.f;
        t.u = pk.y & 0xffff0000u; acc[3] += t.f;
        t.u = pk.z << 16;        acc[4] += t.f;
        t.u = pk.z & 0xffff0000u; acc[5] += t.f;
        t.u = pk.w << 16;        acc[6] += t.f;
        t.u = pk.w & 0xffff0000u; acc[7] += t.f;
    }
#pragma unroll
    for (int j = 0; j < 8; ++j) {
        acc[j] += __shfl_xor(acc[j], 16);
        acc[j] += __shfl_xor(acc[j], 32);
    }
    float ax = (g == 0) ? acc[0] : (g == 1) ? acc[2] : (g == 2) ? acc[4] : acc[6];
    float ay = (g == 0) ? acc[1] : (g == 1) ? acc[3] : (g == 2) ? acc[5] : acc[7];

    const int feat = l * 8 + g * 2;
    const float rd = rdeg[node];
    const float2 base = *(const float2*)(outb + (size_t)node * 128 + feat);
    float ox = base.x + ax * rd;
    float oy = base.y + ay * rd;
    *(float2*)(outb + (size_t)node * 128 + feat) = make_float2(ox, oy);

    const float2 wv2 = *(const float2*)(wfc + feat);
    float p = ox * wv2.x + oy * wv2.y;
#pragma unroll
    for (int off = 32; off > 0; off >>= 1) p += __shfl_down(p, off);
    if (lane == 0) ys[node] = p + bfc[0];
}

extern "C" void kernel_launch(void* const* d_in, const int* in_sizes, int n_in,
                              void* d_out, int out_size, void* d_ws, size_t ws_size,
                              hipStream_t stream)
{
    const float* x   = (const float*)d_in[0];
    const int*   ei  = (const int*)d_in[1];
    const float* Wl  = (const float*)d_in[2];
    const float* bl  = (const float*)d_in[3];
    const float* Wr  = (const float*)d_in[4];
    const float* Wfc = (const float*)d_in[5];
    const float* bfc = (const float*)d_in[6];

    const int N = in_sizes[0] / (S_STEPS * D);
    const int E = in_sizes[1] / 2;
    const int* srcp = ei;
    const int* dstp = ei + E;

    char* p = (char*)d_ws;
    auto alloc = [&](size_t bytes) {
        char* r = p;
        p += (bytes + 255) & ~(size_t)255;
        return r;
    };
    int*   cnt     = (int*)alloc((size_t)N * 4);
    int*   row_ptr = (int*)alloc((size_t)(N + 1) * 4);
    int*   fill    = (int*)alloc((size_t)N * 4);
    float* rdeg    = (float*)alloc((size_t)N * 4);
    int*   eidx    = (int*)alloc((size_t)E * 4);
    unsigned short* wmat = (unsigned short*)alloc((size_t)256 * 128 * 2);

    // v4 needs two node-major tables: xbf + aggx, each [N][S][128] bf16 (~102 MB)
    size_t used = (size_t)(p - (char*)d_ws);
    size_t tbl = (size_t)N * S_STEPS * D * 2;
    bool v4 = (ws_size >= used + 2 * tbl + 4096);

    float* xs    = (float*)d_out;
    float* ysall = xs + (size_t)S_STEPS * N * D;

    (void)hipMemsetAsync(cnt, 0, (size_t)N * 4, stream);
    count_kernel<<<(E + 255) / 256, 256, 0, stream>>>(dstp, cnt, E);
    scan_kernel<<<1, 1024, 0, stream>>>(cnt, row_ptr, fill, rdeg, N, E);
    fill_kernel<<<(E + 255) / 256, 256, 0, stream>>>(srcp, dstp, fill, eidx, E);

    if (v4) {
        unsigned short* xbf  = (unsigned short*)alloc(tbl);
        unsigned short* aggx = (unsigned short*)alloc(tbl);
        cvtwcat_kernel<<<128, 256, 0, stream>>>(Wl, Wr, wmat);
        cvtx_kernel<<<(N + 3) / 4, 256, 0, stream>>>(x, xbf, N);
        agg8x_kernel<<<(N + 3) / 4, 256, 0, stream>>>(xbf, row_ptr, eidx, rdeg,
                                                      aggx, N);
        lin2_kernel<<<(N + 7) / 8, 256, 0, stream>>>(aggx, xbf, wmat, bl, Wfc, bfc,
                                                     xs, ysall, N);
    } else {
        unsigned short* hbf = (unsigned short*)alloc((size_t)N * D * 2);
        cvtw_kernel<<<128, 256, 0, stream>>>(Wl, Wr, wmat);
        const int gl = (N + 63) / 64;
        const int ga = (N + 3) / 4;
        for (int t = 0; t < S_STEPS; ++t) {
            const float* xt = x + (size_t)t * N * D;
            float* outb = xs + (size_t)t * N * D;
            lin_kernel<<<gl, 256, 0, stream>>>(xt, wmat, bl, hbf, outb, N, 1, 0);
            agg_kernel<<<ga, 256, 0, stream>>>(hbf, row_ptr, eidx, rdeg, Wfc, bfc,
                                               outb, ysall + (size_t)t * N, N);
        }
    }
}

// Round 5
// 1122.477 us; speedup vs baseline: 1.1086x; 1.0168x over previous
//
#include <hip/hip_runtime.h>

#define S_STEPS 8
#define D 128

typedef __attribute__((ext_vector_type(4))) float f32x4;
typedef __attribute__((ext_vector_type(4))) short s16x4;
typedef __attribute__((ext_vector_type(8))) short s16x8;

static __device__ __forceinline__ short f2bf(float f) {
    union { float f; unsigned u; } x; x.f = f;
    unsigned r = x.u + 0x7fffu + ((x.u >> 16) & 1u);
    return (short)(r >> 16);
}

__global__ void count_kernel(const int* __restrict__ dst, int* __restrict__ cnt, int E) {
    int e = blockIdx.x * blockDim.x + threadIdx.x;
    if (e < E) atomicAdd(&cnt[dst[e]], 1);
}

// bf16 conversion of [Wl;Wr] -> wbf[256][128] (v0 fallback path)
__global__ void cvtw_kernel(const float* __restrict__ Wl, const float* __restrict__ Wr,
                            unsigned short* __restrict__ wbf) {
    int i = blockIdx.x * blockDim.x + threadIdx.x;   // 0..32767
    if (i < 256 * 128) {
        int j = i >> 7, k = i & 127;
        float v = (j < 128) ? Wl[j * 128 + k] : Wr[(j - 128) * 128 + k];
        wbf[i] = (unsigned short)f2bf(v);
    }
}

// wcat[128][256]: row j = [Wl[j][0:128] | Wr[j][0:128]] in bf16
__global__ void cvtwcat_kernel(const float* __restrict__ Wl, const float* __restrict__ Wr,
                               unsigned short* __restrict__ wcat) {
    int i = blockIdx.x * blockDim.x + threadIdx.x;   // 0..32767
    if (i < 128 * 256) {
        int j = i >> 8, k = i & 255;
        float v = (k < 128) ? Wl[j * 128 + k] : Wr[j * 128 + (k - 128)];
        wcat[i] = (unsigned short)f2bf(v);
    }
}

// v5: x [S][N][128] fp32 -> two half tables xbf{A,B} [N][4][128] bf16 (node-major).
__global__ __launch_bounds__(256) void cvtx_kernel(const float* __restrict__ x,
    unsigned short* __restrict__ xbfA, unsigned short* __restrict__ xbfB, int N)
{
    const int lane = threadIdx.x & 63;
    const int wv = threadIdx.x >> 6;
    const int node = blockIdx.x * 4 + wv;
    if (node >= N) return;
#pragma unroll
    for (int t = 0; t < S_STEPS; ++t) {
        float2 v = *(const float2*)(x + ((size_t)t * N + node) * 128 + lane * 2);
        ushort2 u;
        u.x = (unsigned short)f2bf(v.x);
        u.y = (unsigned short)f2bf(v.y);
        unsigned short* tb = (t < 4) ? xbfA : xbfB;
        *(ushort2*)(tb + ((size_t)node * 4 + (t & 3)) * 128 + lane * 2) = u;
    }
}

// Single-block scan over cnt -> row_ptr (exclusive), fill init, rdeg. Shuffle-based.
__global__ __launch_bounds__(1024) void scan_kernel(const int* __restrict__ cnt,
                            int* __restrict__ row_ptr,
                            int* __restrict__ fill, float* __restrict__ rdeg,
                            int N, int E) {
    __shared__ int wsum[16];
    __shared__ int woff[16];
    __shared__ int carry_s;
    const int tid = threadIdx.x;
    const int lane = tid & 63;
    const int wv = tid >> 6;
    if (tid == 0) carry_s = 0;
    __syncthreads();
    for (int base = 0; base < N; base += 1024) {
        int i = base + tid;
        int v = (i < N) ? cnt[i] : 0;
        int inc = v;
#pragma unroll
        for (int off = 1; off < 64; off <<= 1) {
            int t = __shfl_up(inc, off);
            if (lane >= off) inc += t;
        }
        if (lane == 63) wsum[wv] = inc;
        __syncthreads();
        if (wv == 0 && lane < 16) {
            int s = wsum[lane];
            int in2 = s;
#pragma unroll
            for (int off = 1; off < 16; off <<= 1) {
                int t = __shfl_up(in2, off);
                if (lane >= off) in2 += t;
            }
            woff[lane] = in2 - s;   // exclusive wave offset
        }
        __syncthreads();
        int carry = carry_s;
        int excl = carry + woff[wv] + inc - v;
        if (i < N) {
            row_ptr[i] = excl;
            fill[i] = excl;
            rdeg[i] = 1.0f / (float)((v > 1) ? v : 1);
        }
        __syncthreads();            // everyone read carry_s before update
        if (tid == 1023) carry_s = carry + woff[15] + inc;
        __syncthreads();
    }
    if (tid == 0) row_ptr[N] = E;
}

__global__ void fill_kernel(const int* __restrict__ src, const int* __restrict__ dst,
                            int* __restrict__ fill, int* __restrict__ eidx, int E) {
    int e = blockIdx.x * blockDim.x + threadIdx.x;
    if (e < E) {
        int p = atomicAdd(&fill[dst[e]], 1);
        eidx[p] = src[e];
    }
}

// v0 fallback: C[N,256] = bf16(x[N,128]) @ wbf^T.
__global__ __launch_bounds__(256) void lin_kernel(const float* __restrict__ x,
    const unsigned short* __restrict__ wbf, const float* __restrict__ bl,
    unsigned short* __restrict__ hbf, float* __restrict__ outb, int N,
    int SF, int tf)
{
    __shared__ __align__(16) short As[64 * 136];   // pitch 136 -> bank spread
    __shared__ float bls[128];

    const int tid = threadIdx.x;
    const int row0 = blockIdx.x * 64;
    const int lane = tid & 63;
    const int w = tid >> 6;
    const int m = lane & 15;
    const int q = lane >> 4;

    s16x8 bf[4][4];
#pragma unroll
    for (int ct = 0; ct < 4; ++ct) {
#pragma unroll
        for (int kc = 0; kc < 4; ++kc) {
            int col = (w * 4 + ct) * 16 + m;
            bf[ct][kc] = *(const s16x8*)(wbf + (size_t)col * 128 + kc * 32 + q * 8);
        }
    }
    if (tid < 128) bls[tid] = bl[tid];

#pragma unroll
    for (int it = 0; it < 8; ++it) {
        int i = tid + it * 256;            // 0..2047
        int r = i >> 5;                    // local row
        int kq = i & 31;                   // float4 index along K
        int grow = row0 + r;
        float4 v = make_float4(0.f, 0.f, 0.f, 0.f);
        if (grow < N) v = *(const float4*)(x + (size_t)grow * 128 + kq * 4);
        s16x4 a; a.x = f2bf(v.x); a.y = f2bf(v.y); a.z = f2bf(v.z); a.w = f2bf(v.w);
        *(s16x4*)&As[r * 136 + kq * 4] = a;
    }
    __syncthreads();

    f32x4 acc[4][4];
#pragma unroll
    for (int i = 0; i < 4; ++i)
#pragma unroll
        for (int j = 0; j < 4; ++j) acc[i][j] = (f32x4){0.f, 0.f, 0.f, 0.f};

#pragma unroll
    for (int mt = 0; mt < 4; ++mt) {
        s16x8 af[4];
#pragma unroll
        for (int kc = 0; kc < 4; ++kc)
            af[kc] = *(const s16x8*)&As[(mt * 16 + m) * 136 + kc * 32 + q * 8];
#pragma unroll
        for (int ct = 0; ct < 4; ++ct)
#pragma unroll
            for (int kc = 0; kc < 4; ++kc)
                acc[mt][ct] = __builtin_amdgcn_mfma_f32_16x16x32_bf16(
                    af[kc], bf[ct][kc], acc[mt][ct], 0, 0, 0);
    }

    const int colbase = w * 64;
#pragma unroll
    for (int mt = 0; mt < 4; ++mt) {
        const int rowbase = row0 + mt * 16 + q * 4;
#pragma unroll
        for (int ct = 0; ct < 4; ++ct) {
            int col = colbase + ct * 16 + m;
#pragma unroll
            for (int r = 0; r < 4; ++r) {
                int rr = rowbase + r;
                if (rr < N) {
                    if (col < 128) {
                        hbf[((size_t)rr * SF + tf) * 128 + col] =
                            (unsigned short)f2bf(acc[mt][ct][r]);
                    } else {
                        outb[(size_t)rr * 128 + (col - 128)] = acc[mt][ct][r] + bls[col - 128];
                    }
                }
            }
        }
    }
}

#define BF2ACC(u, j) { union { unsigned v; float f; } lo_, hi_; \
    lo_.v = (u) << 16; hi_.v = (u) & 0xffff0000u; \
    acc[j] += lo_.f; acc[(j) + 1] += hi_.f; }
#define ACC8(p, j) { BF2ACC((p).x, (j)); BF2ACC((p).y, (j) + 2); \
    BF2ACC((p).z, (j) + 4); BF2ACC((p).w, (j) + 6); }

// v5: fused 4-step gather over one half table (1KB node rows). One wave per
// node; lane l reads ONE dwordx4 at byte l*16 of the row -> 8 lanes per 128B
// line, one instruction: perfectly coalesced. 4-edge unroll for MLP.
// Lane l owns step (l>>4), feats (l&15)*8 .. +7.
__global__ __launch_bounds__(256) void agg4x_kernel(const unsigned short* __restrict__ xbfH,
    const int* __restrict__ row_ptr, const int* __restrict__ eidx,
    const float* __restrict__ rdeg, unsigned short* __restrict__ aggxH, int N)
{
    const int lane = threadIdx.x & 63;
    const int wv = threadIdx.x >> 6;
    const int node = blockIdx.x * 4 + wv;
    if (node >= N) return;

    const int beg = row_ptr[node];
    const int end = row_ptr[node + 1];

    float acc[8];
#pragma unroll
    for (int j = 0; j < 8; ++j) acc[j] = 0.f;

    const uint4* hb = (const uint4*)xbfH;   // node row = 64 uint4 (1KB)

    int e = beg;
    for (; e + 4 <= end; e += 4) {
        int s0 = eidx[e];
        int s1 = eidx[e + 1];
        int s2 = eidx[e + 2];
        int s3 = eidx[e + 3];
        uint4 a = hb[(size_t)s0 * 64 + lane];
        uint4 b = hb[(size_t)s1 * 64 + lane];
        uint4 c = hb[(size_t)s2 * 64 + lane];
        uint4 d = hb[(size_t)s3 * 64 + lane];
        ACC8(a, 0); ACC8(b, 0); ACC8(c, 0); ACC8(d, 0);
    }
    for (; e < end; ++e) {
        int s0 = eidx[e];
        uint4 a = hb[(size_t)s0 * 64 + lane];
        ACC8(a, 0);
    }

    const float rd = rdeg[node];
    unsigned short* orow = aggxH + ((size_t)node * 4 + (lane >> 4)) * 128 + (lane & 15) * 8;
    s16x8 o;
#pragma unroll
    for (int j = 0; j < 8; ++j) o[j] = f2bf(acc[j] * rd);
    __builtin_nontemporal_store(o, (s16x8*)orow);
}

// out[row=(n,t)][128] = [aggx|xbf] @ wcat^T + bl ; ys = out . wfc + bfc.
// M-tile = 64 rows = 8 nodes x 8 steps (steps split across half tables);
// K = 256; 4 waves each own 32 out-cols.
__global__ __launch_bounds__(256) void lin2_kernel(
    const unsigned short* __restrict__ aggxA, const unsigned short* __restrict__ aggxB,
    const unsigned short* __restrict__ xbfA, const unsigned short* __restrict__ xbfB,
    const unsigned short* __restrict__ wcat, const float* __restrict__ bl,
    const float* __restrict__ wfc, const float* __restrict__ bfc,
    float* __restrict__ xs, float* __restrict__ ys, int N)
{
    __shared__ __align__(16) short As[64 * 264];   // pitch 264 -> bank spread
    __shared__ float bls[128];
    __shared__ float wfs[128];
    __shared__ float part[4][64];

    const int tid = threadIdx.x;
    const int node0 = blockIdx.x * 8;
    const int lane = tid & 63;
    const int w = tid >> 6;
    const int m = lane & 15;
    const int q = lane >> 4;

    // B frags: wave w owns out-cols w*32 .. w*32+31, K=256 in 8 chunks
    s16x8 bf[2][8];
#pragma unroll
    for (int ct = 0; ct < 2; ++ct) {
#pragma unroll
        for (int kc = 0; kc < 8; ++kc) {
            int col = w * 32 + ct * 16 + m;
            bf[ct][kc] = *(const s16x8*)(wcat + (size_t)col * 256 + kc * 32 + q * 8);
        }
    }
    if (tid < 128) { bls[tid] = bl[tid]; wfs[tid] = wfc[tid]; }

    // stage A: 8 nodes; left half <- aggx node row, right half <- xbf
#pragma unroll
    for (int it = 0; it < 4; ++it) {
        int c = tid + it * 256;            // 0..1023
        int nl = c >> 7;                   // 0..7 local node
        int j = c & 127;                   // 16B chunk within (node,step) space
        int t = j >> 4;                    // 0..7 step
        int k16 = j & 15;
        int row = nl * 8 + t;
        int node = node0 + nl;
        s16x8 va = (s16x8){0,0,0,0,0,0,0,0};
        s16x8 vx = (s16x8){0,0,0,0,0,0,0,0};
        if (node < N) {
            const unsigned short* at = (t < 4) ? aggxA : aggxB;
            const unsigned short* xt = (t < 4) ? xbfA : xbfB;
            size_t src = ((size_t)node * 4 + (t & 3)) * 128 + k16 * 8;
            va = *(const s16x8*)(at + src);
            vx = *(const s16x8*)(xt + src);
        }
        *(s16x8*)&As[row * 264 + k16 * 8] = va;
        *(s16x8*)&As[row * 264 + 128 + k16 * 8] = vx;
    }
    __syncthreads();

    f32x4 acc[4][2];
#pragma unroll
    for (int i = 0; i < 4; ++i)
#pragma unroll
        for (int j = 0; j < 2; ++j) acc[i][j] = (f32x4){0.f, 0.f, 0.f, 0.f};

#pragma unroll
    for (int mt = 0; mt < 4; ++mt) {
        s16x8 af[8];
#pragma unroll
        for (int kc = 0; kc < 8; ++kc)
            af[kc] = *(const s16x8*)&As[(mt * 16 + m) * 264 + kc * 32 + q * 8];
#pragma unroll
        for (int ct = 0; ct < 2; ++ct)
#pragma unroll
            for (int kc = 0; kc < 8; ++kc)
                acc[mt][ct] = __builtin_amdgcn_mfma_f32_16x16x32_bf16(
                    af[kc], bf[ct][kc], acc[mt][ct], 0, 0, 0);
    }

    // epilogue: bias, store xs, partial fc dot
    float pd[4][4];
#pragma unroll
    for (int i = 0; i < 4; ++i)
#pragma unroll
        for (int r = 0; r < 4; ++r) pd[i][r] = 0.f;

    const int colb = w * 32;
#pragma unroll
    for (int mt = 0; mt < 4; ++mt) {
#pragma unroll
        for (int ct = 0; ct < 2; ++ct) {
            int col = colb + ct * 16 + m;
            float blv = bls[col];
            float wfv = wfs[col];
#pragma unroll
            for (int r = 0; r < 4; ++r) {
                int row = mt * 16 + q * 4 + r;     // local row
                int node = node0 + (row >> 3);
                int t = row & 7;
                float o = acc[mt][ct][r] + blv;
                if (node < N) xs[((size_t)t * N + node) * 128 + col] = o;
                pd[mt][r] += o * wfv;
            }
        }
    }
    // reduce partial dots across the 16 m-lanes
#pragma unroll
    for (int off = 1; off < 16; off <<= 1)
#pragma unroll
        for (int mt = 0; mt < 4; ++mt)
#pragma unroll
            for (int r = 0; r < 4; ++r)
                pd[mt][r] += __shfl_xor(pd[mt][r], off);
    if (m == 0) {
#pragma unroll
        for (int mt = 0; mt < 4; ++mt)
#pragma unroll
            for (int r = 0; r < 4; ++r)
                part[w][mt * 16 + q * 4 + r] = pd[mt][r];
    }
    __syncthreads();
    if (tid < 64) {
        int row = tid;
        float v = part[0][row] + part[1][row] + part[2][row] + part[3][row] + bfc[0];
        int node = node0 + (row >> 3);
        int t = row & 7;
        if (node < N) ys[(size_t)t * N + node] = v;
    }
}

// v0 fallback: per-step CSR gather of h (bf16)
__global__ __launch_bounds__(256) void agg_kernel(const unsigned short* __restrict__ hbf,
    const int* __restrict__ row_ptr, const int* __restrict__ eidx,
    const float* __restrict__ rdeg, const float* __restrict__ wfc,
    const float* __restrict__ bfc, float* __restrict__ outb,
    float* __restrict__ ys, int N)
{
    const int lane = threadIdx.x & 63;
    const int wv = threadIdx.x >> 6;
    const int node = blockIdx.x * 4 + wv;
    if (node >= N) return;
    const int g = lane >> 4;
    const int l = lane & 15;
    const int beg = row_ptr[node];
    const int end = row_ptr[node + 1];

    float acc[8];
#pragma unroll
    for (int j = 0; j < 8; ++j) acc[j] = 0.f;

    const unsigned short* hb = hbf + l * 8;
#pragma unroll 2
    for (int e = beg + g; e < end; e += 4) {
        int s = eidx[e];
        uint4 pk = *(const uint4*)(hb + (size_t)s * 128);
        union { unsigned u; float f; } t;
        t.u = pk.x << 16;        acc[0] += t.f;
        t.u = pk.x & 0xffff0000u; acc[1] += t.f;
        t.u = pk.y << 16;        acc[2] += t.f;
        t.u = pk.y & 0xffff0000u; acc[3] += t.f;
        t.u = pk.z << 16;        acc[4] += t.f;
        t.u = pk.z & 0xffff0000u; acc[5] += t.f;
        t.u = pk.w << 16;        acc[6] += t.f;
        t.u = pk.w & 0xffff0000u; acc[7] += t.f;
    }
#pragma unroll
    for (int j = 0; j < 8; ++j) {
        acc[j] += __shfl_xor(acc[j], 16);
        acc[j] += __shfl_xor(acc[j], 32);
    }
    float ax = (g == 0) ? acc[0] : (g == 1) ? acc[2] : (g == 2) ? acc[4] : acc[6];
    float ay = (g == 0) ? acc[1] : (g == 1) ? acc[3] : (g == 2) ? acc[5] : acc[7];

    const int feat = l * 8 + g * 2;
    const float rd = rdeg[node];
    const float2 base = *(const float2*)(outb + (size_t)node * 128 + feat);
    float ox = base.x + ax * rd;
    float oy = base.y + ay * rd;
    *(float2*)(outb + (size_t)node * 128 + feat) = make_float2(ox, oy);

    const float2 wv2 = *(const float2*)(wfc + feat);
    float p = ox * wv2.x + oy * wv2.y;
#pragma unroll
    for (int off = 32; off > 0; off >>= 1) p += __shfl_down(p, off);
    if (lane == 0) ys[node] = p + bfc[0];
}

extern "C" void kernel_launch(void* const* d_in, const int* in_sizes, int n_in,
                              void* d_out, int out_size, void* d_ws, size_t ws_size,
                              hipStream_t stream)
{
    const float* x   = (const float*)d_in[0];
    const int*   ei  = (const int*)d_in[1];
    const float* Wl  = (const float*)d_in[2];
    const float* bl  = (const float*)d_in[3];
    const float* Wr  = (const float*)d_in[4];
    const float* Wfc = (const float*)d_in[5];
    const float* bfc = (const float*)d_in[6];

    const int N = in_sizes[0] / (S_STEPS * D);
    const int E = in_sizes[1] / 2;
    const int* srcp = ei;
    const int* dstp = ei + E;

    char* p = (char*)d_ws;
    auto alloc = [&](size_t bytes) {
        char* r = p;
        p += (bytes + 255) & ~(size_t)255;
        return r;
    };
    int*   cnt     = (int*)alloc((size_t)N * 4);
    int*   row_ptr = (int*)alloc((size_t)(N + 1) * 4);
    int*   fill    = (int*)alloc((size_t)N * 4);
    float* rdeg    = (float*)alloc((size_t)N * 4);
    int*   eidx    = (int*)alloc((size_t)E * 4);
    unsigned short* wmat = (unsigned short*)alloc((size_t)256 * 128 * 2);

    // v5 needs 4 half tables: xbf{A,B} + aggx{A,B}, each [N][4][128] bf16 (~51 MB)
    size_t used = (size_t)(p - (char*)d_ws);
    size_t htbl = (size_t)N * 4 * D * 2;
    bool v5 = (ws_size >= used + 4 * htbl + 4096);

    float* xs    = (float*)d_out;
    float* ysall = xs + (size_t)S_STEPS * N * D;

    (void)hipMemsetAsync(cnt, 0, (size_t)N * 4, stream);
    count_kernel<<<(E + 255) / 256, 256, 0, stream>>>(dstp, cnt, E);
    scan_kernel<<<1, 1024, 0, stream>>>(cnt, row_ptr, fill, rdeg, N, E);
    fill_kernel<<<(E + 255) / 256, 256, 0, stream>>>(srcp, dstp, fill, eidx, E);

    if (v5) {
        unsigned short* xbfA  = (unsigned short*)alloc(htbl);
        unsigned short* xbfB  = (unsigned short*)alloc(htbl);
        unsigned short* aggxA = (unsigned short*)alloc(htbl);
        unsigned short* aggxB = (unsigned short*)alloc(htbl);
        cvtwcat_kernel<<<128, 256, 0, stream>>>(Wl, Wr, wmat);
        cvtx_kernel<<<(N + 3) / 4, 256, 0, stream>>>(x, xbfA, xbfB, N);
        agg4x_kernel<<<(N + 3) / 4, 256, 0, stream>>>(xbfA, row_ptr, eidx, rdeg,
                                                      aggxA, N);
        agg4x_kernel<<<(N + 3) / 4, 256, 0, stream>>>(xbfB, row_ptr, eidx, rdeg,
                                                      aggxB, N);
        lin2_kernel<<<(N + 7) / 8, 256, 0, stream>>>(aggxA, aggxB, xbfA, xbfB,
                                                     wmat, bl, Wfc, bfc,
                                                     xs, ysall, N);
    } else {
        unsigned short* hbf = (unsigned short*)alloc((size_t)N * D * 2);
        cvtw_kernel<<<128, 256, 0, stream>>>(Wl, Wr, wmat);
        const int gl = (N + 63) / 64;
        const int ga = (N + 3) / 4;
        for (int t = 0; t < S_STEPS; ++t) {
            const float* xt = x + (size_t)t * N * D;
            float* outb = xs + (size_t)t * N * D;
            lin_kernel<<<gl, 256, 0, stream>>>(xt, wmat, bl, hbf, outb, N, 1, 0);
            agg_kernel<<<ga, 256, 0, stream>>>(hbf, row_ptr, eidx, rdeg, Wfc, bfc,
                                               outb, ysall + (size_t)t * N, N);
        }
    }
}

// Round 6
// 953.950 us; speedup vs baseline: 1.3045x; 1.1767x over previous
//
#include <hip/hip_runtime.h>

#define S_STEPS 8
#define D 128

typedef __attribute__((ext_vector_type(4))) float f32x4;
typedef __attribute__((ext_vector_type(4))) short s16x4;
typedef __attribute__((ext_vector_type(8))) short s16x8;

static __device__ __forceinline__ short f2bf(float f) {
    union { float f; unsigned u; } x; x.f = f;
    unsigned r = x.u + 0x7fffu + ((x.u >> 16) & 1u);
    return (short)(r >> 16);
}

// ---------------- v6 radix CSR build (no per-edge global atomics) -------------

// R1: 256-wide LDS histogram of dst>>8, flushed once per block.
__global__ __launch_bounds__(256) void bhist_kernel(const int* __restrict__ dst,
    int* __restrict__ bhist, int E)
{
    __shared__ int lh[256];
    lh[threadIdx.x] = 0;
    __syncthreads();
    for (int e = blockIdx.x * 256 + threadIdx.x; e < E; e += gridDim.x * 256)
        atomicAdd(&lh[dst[e] >> 8], 1);
    __syncthreads();
    int v = lh[threadIdx.x];
    if (v) atomicAdd(&bhist[threadIdx.x], v);
}

// R2: single-block exclusive scan of NB bucket counts -> bbase, cursor; row_ptr[N]=E.
__global__ __launch_bounds__(256) void bscan_kernel(const int* __restrict__ bhist,
    int* __restrict__ bbase, int* __restrict__ cursor, int* __restrict__ row_ptr,
    int N, int E, int NB)
{
    __shared__ int wsum[4];
    __shared__ int woff[4];
    const int tid = threadIdx.x;
    const int lane = tid & 63;
    const int wv = tid >> 6;
    int v = (tid < NB) ? bhist[tid] : 0;
    int inc = v;
#pragma unroll
    for (int off = 1; off < 64; off <<= 1) {
        int t = __shfl_up(inc, off);
        if (lane >= off) inc += t;
    }
    if (lane == 63) wsum[wv] = inc;
    __syncthreads();
    if (tid == 0) { int s = 0; for (int k = 0; k < 4; ++k) { woff[k] = s; s += wsum[k]; } }
    __syncthreads();
    int excl = woff[wv] + inc - v;
    if (tid < NB) { bbase[tid] = excl; cursor[tid] = excl; }
    if (tid == NB) bbase[NB] = E;
    if (tid == 0) row_ptr[N] = E;
}

// R3: partition edges into dst-buckets. One global atomic per (block,bucket);
// per-edge work is LDS-only. ebuf entry packs (src<<8)|(dst&255).
__global__ __launch_bounds__(256) void scat_kernel(const int* __restrict__ src,
    const int* __restrict__ dst, int* __restrict__ cursor,
    unsigned* __restrict__ ebuf, int E, int len, int NB)
{
    __shared__ int lh[256];
    __shared__ int lb[256];
    const int tid = threadIdx.x;
    const int e0 = blockIdx.x * len;
    const int e1 = min(E, e0 + len);
    if (e0 >= E) return;
    lh[tid] = 0;
    __syncthreads();
    for (int e = e0 + tid; e < e1; e += 256)
        atomicAdd(&lh[dst[e] >> 8], 1);
    __syncthreads();
    if (tid < NB) lb[tid] = lh[tid] ? atomicAdd(&cursor[tid], lh[tid]) : 0;
    __syncthreads();
    lh[tid] = 0;
    __syncthreads();
    for (int e = e0 + tid; e < e1; e += 256) {
        int d = dst[e];
        int b = d >> 8;
        int off = atomicAdd(&lh[b], 1);
        ebuf[lb[b] + off] = ((unsigned)src[e] << 8) | (unsigned)(d & 255);
    }
}

// R4: one block per bucket: count 256 local dsts, shuffle-scan, emit row_ptr,
// scatter src into eidx (bucket-local LDS cursors).
__global__ __launch_bounds__(256) void bsort_kernel(const unsigned* __restrict__ ebuf,
    const int* __restrict__ bbase, int* __restrict__ row_ptr,
    int* __restrict__ eidx, int N)
{
    __shared__ int cnt[256];
    __shared__ int wsum[4];
    __shared__ int woff[4];
    const int tid = threadIdx.x;
    const int b = blockIdx.x;
    const int base = bbase[b];
    const int K = bbase[b + 1] - base;
    cnt[tid] = 0;
    __syncthreads();
    for (int i = tid; i < K; i += 256)
        atomicAdd(&cnt[ebuf[base + i] & 255], 1);
    __syncthreads();
    int v = cnt[tid];
    int inc = v;
    const int lane = tid & 63;
    const int wv = tid >> 6;
#pragma unroll
    for (int off = 1; off < 64; off <<= 1) {
        int t = __shfl_up(inc, off);
        if (lane >= off) inc += t;
    }
    if (lane == 63) wsum[wv] = inc;
    __syncthreads();
    if (tid == 0) { int s = 0; for (int k = 0; k < 4; ++k) { woff[k] = s; s += wsum[k]; } }
    __syncthreads();
    int excl = woff[wv] + inc - v;
    int node = b * 256 + tid;
    if (node < N) row_ptr[node] = base + excl;
    __syncthreads();
    cnt[tid] = excl;
    __syncthreads();
    for (int i = tid; i < K; i += 256) {
        unsigned u = ebuf[base + i];
        int off = atomicAdd(&cnt[u & 255], 1);
        eidx[base + off] = (int)(u >> 8);
    }
}

// ---------------- v0 fallback CSR build (atomic-based, proven) ----------------

__global__ void count_kernel(const int* __restrict__ dst, int* __restrict__ cnt, int E) {
    int e = blockIdx.x * blockDim.x + threadIdx.x;
    if (e < E) atomicAdd(&cnt[dst[e]], 1);
}

__global__ __launch_bounds__(1024) void scan_kernel(const int* __restrict__ cnt,
                            int* __restrict__ row_ptr,
                            int* __restrict__ fill, float* __restrict__ rdeg,
                            int N, int E) {
    __shared__ int wsum[16];
    __shared__ int woff[16];
    __shared__ int carry_s;
    const int tid = threadIdx.x;
    const int lane = tid & 63;
    const int wv = tid >> 6;
    if (tid == 0) carry_s = 0;
    __syncthreads();
    for (int base = 0; base < N; base += 1024) {
        int i = base + tid;
        int v = (i < N) ? cnt[i] : 0;
        int inc = v;
#pragma unroll
        for (int off = 1; off < 64; off <<= 1) {
            int t = __shfl_up(inc, off);
            if (lane >= off) inc += t;
        }
        if (lane == 63) wsum[wv] = inc;
        __syncthreads();
        if (wv == 0 && lane < 16) {
            int s = wsum[lane];
            int in2 = s;
#pragma unroll
            for (int off = 1; off < 16; off <<= 1) {
                int t = __shfl_up(in2, off);
                if (lane >= off) in2 += t;
            }
            woff[lane] = in2 - s;
        }
        __syncthreads();
        int carry = carry_s;
        int excl = carry + woff[wv] + inc - v;
        if (i < N) {
            row_ptr[i] = excl;
            fill[i] = excl;
            rdeg[i] = 1.0f / (float)((v > 1) ? v : 1);
        }
        __syncthreads();
        if (tid == 1023) carry_s = carry + woff[15] + inc;
        __syncthreads();
    }
    if (tid == 0) row_ptr[N] = E;
}

__global__ void fill_kernel(const int* __restrict__ src, const int* __restrict__ dst,
                            int* __restrict__ fill, int* __restrict__ eidx, int E) {
    int e = blockIdx.x * blockDim.x + threadIdx.x;
    if (e < E) {
        int p = atomicAdd(&fill[dst[e]], 1);
        eidx[p] = src[e];
    }
}

// ---------------- weight/x conversion ----------------

__global__ void cvtw_kernel(const float* __restrict__ Wl, const float* __restrict__ Wr,
                            unsigned short* __restrict__ wbf) {
    int i = blockIdx.x * blockDim.x + threadIdx.x;
    if (i < 256 * 128) {
        int j = i >> 7, k = i & 127;
        float v = (j < 128) ? Wl[j * 128 + k] : Wr[(j - 128) * 128 + k];
        wbf[i] = (unsigned short)f2bf(v);
    }
}

// wcat[128][256]: row j = [Wl[j][0:128] | Wr[j][0:128]] in bf16
__global__ void cvtwcat_kernel(const float* __restrict__ Wl, const float* __restrict__ Wr,
                               unsigned short* __restrict__ wcat) {
    int i = blockIdx.x * blockDim.x + threadIdx.x;
    if (i < 128 * 256) {
        int j = i >> 8, k = i & 255;
        float v = (k < 128) ? Wl[j * 128 + k] : Wr[j * 128 + (k - 128)];
        wcat[i] = (unsigned short)f2bf(v);
    }
}

// x [S][N][128] fp32 -> two half tables xbf{A,B} [N][4][128] bf16 (node-major).
__global__ __launch_bounds__(256) void cvtx_kernel(const float* __restrict__ x,
    unsigned short* __restrict__ xbfA, unsigned short* __restrict__ xbfB, int N)
{
    const int lane = threadIdx.x & 63;
    const int wv = threadIdx.x >> 6;
    const int node = blockIdx.x * 4 + wv;
    if (node >= N) return;
#pragma unroll
    for (int t = 0; t < S_STEPS; ++t) {
        float2 v = *(const float2*)(x + ((size_t)t * N + node) * 128 + lane * 2);
        ushort2 u;
        u.x = (unsigned short)f2bf(v.x);
        u.y = (unsigned short)f2bf(v.y);
        unsigned short* tb = (t < 4) ? xbfA : xbfB;
        *(ushort2*)(tb + ((size_t)node * 4 + (t & 3)) * 128 + lane * 2) = u;
    }
}

// ---------------- v0 fallback compute ----------------

__global__ __launch_bounds__(256) void lin_kernel(const float* __restrict__ x,
    const unsigned short* __restrict__ wbf, const float* __restrict__ bl,
    unsigned short* __restrict__ hbf, float* __restrict__ outb, int N,
    int SF, int tf)
{
    __shared__ __align__(16) short As[64 * 136];
    __shared__ float bls[128];

    const int tid = threadIdx.x;
    const int row0 = blockIdx.x * 64;
    const int lane = tid & 63;
    const int w = tid >> 6;
    const int m = lane & 15;
    const int q = lane >> 4;

    s16x8 bf[4][4];
#pragma unroll
    for (int ct = 0; ct < 4; ++ct) {
#pragma unroll
        for (int kc = 0; kc < 4; ++kc) {
            int col = (w * 4 + ct) * 16 + m;
            bf[ct][kc] = *(const s16x8*)(wbf + (size_t)col * 128 + kc * 32 + q * 8);
        }
    }
    if (tid < 128) bls[tid] = bl[tid];

#pragma unroll
    for (int it = 0; it < 8; ++it) {
        int i = tid + it * 256;
        int r = i >> 5;
        int kq = i & 31;
        int grow = row0 + r;
        float4 v = make_float4(0.f, 0.f, 0.f, 0.f);
        if (grow < N) v = *(const float4*)(x + (size_t)grow * 128 + kq * 4);
        s16x4 a; a.x = f2bf(v.x); a.y = f2bf(v.y); a.z = f2bf(v.z); a.w = f2bf(v.w);
        *(s16x4*)&As[r * 136 + kq * 4] = a;
    }
    __syncthreads();

    f32x4 acc[4][4];
#pragma unroll
    for (int i = 0; i < 4; ++i)
#pragma unroll
        for (int j = 0; j < 4; ++j) acc[i][j] = (f32x4){0.f, 0.f, 0.f, 0.f};

#pragma unroll
    for (int mt = 0; mt < 4; ++mt) {
        s16x8 af[4];
#pragma unroll
        for (int kc = 0; kc < 4; ++kc)
            af[kc] = *(const s16x8*)&As[(mt * 16 + m) * 136 + kc * 32 + q * 8];
#pragma unroll
        for (int ct = 0; ct < 4; ++ct)
#pragma unroll
            for (int kc = 0; kc < 4; ++kc)
                acc[mt][ct] = __builtin_amdgcn_mfma_f32_16x16x32_bf16(
                    af[kc], bf[ct][kc], acc[mt][ct], 0, 0, 0);
    }

    const int colbase = w * 64;
#pragma unroll
    for (int mt = 0; mt < 4; ++mt) {
        const int rowbase = row0 + mt * 16 + q * 4;
#pragma unroll
        for (int ct = 0; ct < 4; ++ct) {
            int col = colbase + ct * 16 + m;
#pragma unroll
            for (int r = 0; r < 4; ++r) {
                int rr = rowbase + r;
                if (rr < N) {
                    if (col < 128) {
                        hbf[((size_t)rr * SF + tf) * 128 + col] =
                            (unsigned short)f2bf(acc[mt][ct][r]);
                    } else {
                        outb[(size_t)rr * 128 + (col - 128)] = acc[mt][ct][r] + bls[col - 128];
                    }
                }
            }
        }
    }
}

#define BF2ACC(u, j) { union { unsigned v; float f; } lo_, hi_; \
    lo_.v = (u) << 16; hi_.v = (u) & 0xffff0000u; \
    acc[j] += lo_.f; acc[(j) + 1] += hi_.f; }
#define ACC8(p, j) { BF2ACC((p).x, (j)); BF2ACC((p).y, (j) + 2); \
    BF2ACC((p).z, (j) + 4); BF2ACC((p).w, (j) + 6); }

// Fused 4-step gather over one half table (1KB node rows, coalesced dwordx4/lane).
__global__ __launch_bounds__(256) void agg4x_kernel(const unsigned short* __restrict__ xbfH,
    const int* __restrict__ row_ptr, const int* __restrict__ eidx,
    unsigned short* __restrict__ aggxH, int N)
{
    const int lane = threadIdx.x & 63;
    const int wv = threadIdx.x >> 6;
    const int node = blockIdx.x * 4 + wv;
    if (node >= N) return;

    const int beg = row_ptr[node];
    const int end = row_ptr[node + 1];

    float acc[8];
#pragma unroll
    for (int j = 0; j < 8; ++j) acc[j] = 0.f;

    const uint4* hb = (const uint4*)xbfH;

    int e = beg;
    for (; e + 4 <= end; e += 4) {
        int s0 = eidx[e];
        int s1 = eidx[e + 1];
        int s2 = eidx[e + 2];
        int s3 = eidx[e + 3];
        uint4 a = hb[(size_t)s0 * 64 + lane];
        uint4 b = hb[(size_t)s1 * 64 + lane];
        uint4 c = hb[(size_t)s2 * 64 + lane];
        uint4 d = hb[(size_t)s3 * 64 + lane];
        ACC8(a, 0); ACC8(b, 0); ACC8(c, 0); ACC8(d, 0);
    }
    for (; e < end; ++e) {
        int s0 = eidx[e];
        uint4 a = hb[(size_t)s0 * 64 + lane];
        ACC8(a, 0);
    }

    int deg = end - beg;
    const float rd = 1.0f / (float)((deg > 1) ? deg : 1);
    unsigned short* orow = aggxH + ((size_t)node * 4 + (lane >> 4)) * 128 + (lane & 15) * 8;
    s16x8 o;
#pragma unroll
    for (int j = 0; j < 8; ++j) o[j] = f2bf(acc[j] * rd);
    __builtin_nontemporal_store(o, (s16x8*)orow);
}

// out[row=(n,t)][128] = [aggx|xbf] @ wcat^T + bl ; ys = out . wfc + bfc.
__global__ __launch_bounds__(256) void lin2_kernel(
    const unsigned short* __restrict__ aggxA, const unsigned short* __restrict__ aggxB,
    const unsigned short* __restrict__ xbfA, const unsigned short* __restrict__ xbfB,
    const unsigned short* __restrict__ wcat, const float* __restrict__ bl,
    const float* __restrict__ wfc, const float* __restrict__ bfc,
    float* __restrict__ xs, float* __restrict__ ys, int N)
{
    __shared__ __align__(16) short As[64 * 264];
    __shared__ float bls[128];
    __shared__ float wfs[128];
    __shared__ float part[4][64];

    const int tid = threadIdx.x;
    const int node0 = blockIdx.x * 8;
    const int lane = tid & 63;
    const int w = tid >> 6;
    const int m = lane & 15;
    const int q = lane >> 4;

    s16x8 bf[2][8];
#pragma unroll
    for (int ct = 0; ct < 2; ++ct) {
#pragma unroll
        for (int kc = 0; kc < 8; ++kc) {
            int col = w * 32 + ct * 16 + m;
            bf[ct][kc] = *(const s16x8*)(wcat + (size_t)col * 256 + kc * 32 + q * 8);
        }
    }
    if (tid < 128) { bls[tid] = bl[tid]; wfs[tid] = wfc[tid]; }

#pragma unroll
    for (int it = 0; it < 4; ++it) {
        int c = tid + it * 256;
        int nl = c >> 7;
        int j = c & 127;
        int t = j >> 4;
        int k16 = j & 15;
        int row = nl * 8 + t;
        int node = node0 + nl;
        s16x8 va = (s16x8){0,0,0,0,0,0,0,0};
        s16x8 vx = (s16x8){0,0,0,0,0,0,0,0};
        if (node < N) {
            const unsigned short* at = (t < 4) ? aggxA : aggxB;
            const unsigned short* xt = (t < 4) ? xbfA : xbfB;
            size_t src = ((size_t)node * 4 + (t & 3)) * 128 + k16 * 8;
            va = *(const s16x8*)(at + src);
            vx = *(const s16x8*)(xt + src);
        }
        *(s16x8*)&As[row * 264 + k16 * 8] = va;
        *(s16x8*)&As[row * 264 + 128 + k16 * 8] = vx;
    }
    __syncthreads();

    f32x4 acc[4][2];
#pragma unroll
    for (int i = 0; i < 4; ++i)
#pragma unroll
        for (int j = 0; j < 2; ++j) acc[i][j] = (f32x4){0.f, 0.f, 0.f, 0.f};

#pragma unroll
    for (int mt = 0; mt < 4; ++mt) {
        s16x8 af[8];
#pragma unroll
        for (int kc = 0; kc < 8; ++kc)
            af[kc] = *(const s16x8*)&As[(mt * 16 + m) * 264 + kc * 32 + q * 8];
#pragma unroll
        for (int ct = 0; ct < 2; ++ct)
#pragma unroll
            for (int kc = 0; kc < 8; ++kc)
                acc[mt][ct] = __builtin_amdgcn_mfma_f32_16x16x32_bf16(
                    af[kc], bf[ct][kc], acc[mt][ct], 0, 0, 0);
    }

    float pd[4][4];
#pragma unroll
    for (int i = 0; i < 4; ++i)
#pragma unroll
        for (int r = 0; r < 4; ++r) pd[i][r] = 0.f;

    const int colb = w * 32;
#pragma unroll
    for (int mt = 0; mt < 4; ++mt) {
#pragma unroll
        for (int ct = 0; ct < 2; ++ct) {
            int col = colb + ct * 16 + m;
            float blv = bls[col];
            float wfv = wfs[col];
#pragma unroll
            for (int r = 0; r < 4; ++r) {
                int row = mt * 16 + q * 4 + r;
                int node = node0 + (row >> 3);
                int t = row & 7;
                float o = acc[mt][ct][r] + blv;
                if (node < N) xs[((size_t)t * N + node) * 128 + col] = o;
                pd[mt][r] += o * wfv;
            }
        }
    }
#pragma unroll
    for (int off = 1; off < 16; off <<= 1)
#pragma unroll
        for (int mt = 0; mt < 4; ++mt)
#pragma unroll
            for (int r = 0; r < 4; ++r)
                pd[mt][r] += __shfl_xor(pd[mt][r], off);
    if (m == 0) {
#pragma unroll
        for (int mt = 0; mt < 4; ++mt)
#pragma unroll
            for (int r = 0; r < 4; ++r)
                part[w][mt * 16 + q * 4 + r] = pd[mt][r];
    }
    __syncthreads();
    if (tid < 64) {
        int row = tid;
        float v = part[0][row] + part[1][row] + part[2][row] + part[3][row] + bfc[0];
        int node = node0 + (row >> 3);
        int t = row & 7;
        if (node < N) ys[(size_t)t * N + node] = v;
    }
}

// v0 fallback: per-step CSR gather of h (bf16)
__global__ __launch_bounds__(256) void agg_kernel(const unsigned short* __restrict__ hbf,
    const int* __restrict__ row_ptr, const int* __restrict__ eidx,
    const float* __restrict__ rdeg, const float* __restrict__ wfc,
    const float* __restrict__ bfc, float* __restrict__ outb,
    float* __restrict__ ys, int N)
{
    const int lane = threadIdx.x & 63;
    const int wv = threadIdx.x >> 6;
    const int node = blockIdx.x * 4 + wv;
    if (node >= N) return;
    const int g = lane >> 4;
    const int l = lane & 15;
    const int beg = row_ptr[node];
    const int end = row_ptr[node + 1];

    float acc[8];
#pragma unroll
    for (int j = 0; j < 8; ++j) acc[j] = 0.f;

    const unsigned short* hb = hbf + l * 8;
#pragma unroll 2
    for (int e = beg + g; e < end; e += 4) {
        int s = eidx[e];
        uint4 pk = *(const uint4*)(hb + (size_t)s * 128);
        union { unsigned u; float f; } t;
        t.u = pk.x << 16;        acc[0] += t.f;
        t.u = pk.x & 0xffff0000u; acc[1] += t.f;
        t.u = pk.y << 16;        acc[2] += t.f;
        t.u = pk.y & 0xffff0000u; acc[3] += t.f;
        t.u = pk.z << 16;        acc[4] += t.f;
        t.u = pk.z & 0xffff0000u; acc[5] += t.f;
        t.u = pk.w << 16;        acc[6] += t.f;
        t.u = pk.w & 0xffff0000u; acc[7] += t.f;
    }
#pragma unroll
    for (int j = 0; j < 8; ++j) {
        acc[j] += __shfl_xor(acc[j], 16);
        acc[j] += __shfl_xor(acc[j], 32);
    }
    float ax = (g == 0) ? acc[0] : (g == 1) ? acc[2] : (g == 2) ? acc[4] : acc[6];
    float ay = (g == 0) ? acc[1] : (g == 1) ? acc[3] : (g == 2) ? acc[5] : acc[7];

    const int feat = l * 8 + g * 2;
    const float rd = rdeg[node];
    const float2 base = *(const float2*)(outb + (size_t)node * 128 + feat);
    float ox = base.x + ax * rd;
    float oy = base.y + ay * rd;
    *(float2*)(outb + (size_t)node * 128 + feat) = make_float2(ox, oy);

    const float2 wv2 = *(const float2*)(wfc + feat);
    float p = ox * wv2.x + oy * wv2.y;
#pragma unroll
    for (int off = 32; off > 0; off >>= 1) p += __shfl_down(p, off);
    if (lane == 0) ys[node] = p + bfc[0];
}

extern "C" void kernel_launch(void* const* d_in, const int* in_sizes, int n_in,
                              void* d_out, int out_size, void* d_ws, size_t ws_size,
                              hipStream_t stream)
{
    const float* x   = (const float*)d_in[0];
    const int*   ei  = (const int*)d_in[1];
    const float* Wl  = (const float*)d_in[2];
    const float* bl  = (const float*)d_in[3];
    const float* Wr  = (const float*)d_in[4];
    const float* Wfc = (const float*)d_in[5];
    const float* bfc = (const float*)d_in[6];

    const int N = in_sizes[0] / (S_STEPS * D);
    const int E = in_sizes[1] / 2;
    const int* srcp = ei;
    const int* dstp = ei + E;

    char* p = (char*)d_ws;
    auto alloc = [&](size_t bytes) {
        char* r = p;
        p += (bytes + 255) & ~(size_t)255;
        return r;
    };
    int*   row_ptr = (int*)alloc((size_t)(N + 1) * 4);
    int*   eidx    = (int*)alloc((size_t)E * 4);
    unsigned short* wmat = (unsigned short*)alloc((size_t)256 * 128 * 2);

    const int NB = (N + 255) >> 8;
    size_t used = (size_t)(p - (char*)d_ws);
    size_t htbl = (size_t)N * 4 * D * 2;                   // one half table ~51 MB
    size_t radix = ((size_t)E * 4 + 256) + 3 * ((size_t)(NB + 1) * 4 + 256);
    bool v6 = (NB >= 1) && (NB < 256) && (N < (1 << 24)) &&
              (ws_size >= used + radix + 4 * htbl + 65536);

    float* xs    = (float*)d_out;
    float* ysall = xs + (size_t)S_STEPS * N * D;

    if (v6) {
        unsigned* ebuf = (unsigned*)alloc((size_t)E * 4);
        int* bhist  = (int*)alloc((size_t)(NB + 1) * 4);
        int* bbase  = (int*)alloc((size_t)(NB + 1) * 4);
        int* cursor = (int*)alloc((size_t)(NB + 1) * 4);
        unsigned short* xbfA  = (unsigned short*)alloc(htbl);
        unsigned short* xbfB  = (unsigned short*)alloc(htbl);
        unsigned short* aggxA = (unsigned short*)alloc(htbl);
        unsigned short* aggxB = (unsigned short*)alloc(htbl);

        (void)hipMemsetAsync(bhist, 0, (size_t)NB * 4, stream);
        bhist_kernel<<<384, 256, 0, stream>>>(dstp, bhist, E);
        bscan_kernel<<<1, 256, 0, stream>>>(bhist, bbase, cursor, row_ptr, N, E, NB);
        const int len = (E + 511) / 512;
        scat_kernel<<<512, 256, 0, stream>>>(srcp, dstp, cursor, ebuf, E, len, NB);
        bsort_kernel<<<NB, 256, 0, stream>>>(ebuf, bbase, row_ptr, eidx, N);

        cvtwcat_kernel<<<128, 256, 0, stream>>>(Wl, Wr, wmat);
        cvtx_kernel<<<(N + 3) / 4, 256, 0, stream>>>(x, xbfA, xbfB, N);
        agg4x_kernel<<<(N + 3) / 4, 256, 0, stream>>>(xbfA, row_ptr, eidx, aggxA, N);
        agg4x_kernel<<<(N + 3) / 4, 256, 0, stream>>>(xbfB, row_ptr, eidx, aggxB, N);
        lin2_kernel<<<(N + 7) / 8, 256, 0, stream>>>(aggxA, aggxB, xbfA, xbfB,
                                                     wmat, bl, Wfc, bfc,
                                                     xs, ysall, N);
    } else {
        int*   cnt  = (int*)alloc((size_t)N * 4);
        int*   fill = (int*)alloc((size_t)N * 4);
        float* rdeg = (float*)alloc((size_t)N * 4);
        unsigned short* hbf = (unsigned short*)alloc((size_t)N * D * 2);

        (void)hipMemsetAsync(cnt, 0, (size_t)N * 4, stream);
        count_kernel<<<(E + 255) / 256, 256, 0, stream>>>(dstp, cnt, E);
        scan_kernel<<<1, 1024, 0, stream>>>(cnt, row_ptr, fill, rdeg, N, E);
        fill_kernel<<<(E + 255) / 256, 256, 0, stream>>>(srcp, dstp, fill, eidx, E);
        cvtw_kernel<<<128, 256, 0, stream>>>(Wl, Wr, wmat);
        const int gl = (N + 63) / 64;
        const int ga = (N + 3) / 4;
        for (int t = 0; t < S_STEPS; ++t) {
            const float* xt = x + (size_t)t * N * D;
            float* outb = xs + (size_t)t * N * D;
            lin_kernel<<<gl, 256, 0, stream>>>(xt, wmat, bl, hbf, outb, N, 1, 0);
            agg_kernel<<<ga, 256, 0, stream>>>(hbf, row_ptr, eidx, rdeg, Wfc, bfc,
                                               outb, ysall + (size_t)t * N, N);
        }
    }
}